// Round 4
// baseline (2707.064 us; speedup 1.0000x reference)
//
#include <hip/hip_runtime.h>
#include <math.h>

// DeepArcNet fused kernel, R10b: identical to R10 (bench never ran --
// GPUAcquisitionTimeout; resubmitting unmodified so the next measurement
// is uncontaminated).
// R9 post-mortem: scalar s_loads return OUT-OF-ORDER -> every use forces
// lgkmcnt(0) full drain -> serialized weight stream (VALUBusy 10%).
// Root problem across R7-R9: grid of 3277 waves = 3.2 waves/SIMD average;
// nothing hides latency at that occupancy.
// R10: 2 lanes per token (e-halves), 12 lanes/item, 5 items/wave ->
// 6554 waves (6.4/SIMD). Halves: g0 owns e[0,32)+4 zero-pad, g1 owns
// e[32,68) -> every weight slice (row*68 + 32g floats) stays 16B-aligned,
// all loops uniform 36 (zero-pad kills the overlap contribution), no
// divergent trip counts. Weights via per-lane vector loads (vmcnt,
// in-order, deep pipelining, L1-resident). Pair combines via shfl_xor(1).
// QKV+scores STREAMED per d: k/q/v partial dots -> shfl combine -> k
// exchanged through a 1-float LDS slot -> scores accumulated; no q/k LDS
// arrays. LDS = 36 rows x 69 = 9.9KB/wave. Rule-20 discipline: rolled
// producers write LDS rows only; register arrays (h, av, attn_own, z, sc)
// indexed compile-time only (unrolled copies from LDS).

#define ROWW 69   // row stride (floats): v[0,34) | gather[35,69) | kcur@64

// dot of 36-elem register vector with 16B-aligned global slice
__device__ __forceinline__ float dot36g(const float (&h)[36],
                                        const float* __restrict__ w) {
    float a0 = 0.f, a1 = 0.f, a2 = 0.f, a3 = 0.f;
#pragma unroll
    for (int e = 0; e < 36; e += 4) {
        const float4 wv = *(const float4*)(w + e);
        a0 = fmaf(h[e + 0], wv.x, a0);
        a1 = fmaf(h[e + 1], wv.y, a1);
        a2 = fmaf(h[e + 2], wv.z, a2);
        a3 = fmaf(h[e + 3], wv.w, a3);
    }
    return (a0 + a1) + (a2 + a3);
}

// dot of 34-elem register vector with 8B-aligned global row (ff2 rows)
__device__ __forceinline__ float dot34g2(const float (&z)[34],
                                         const float* __restrict__ w) {
    float a0 = 0.f, a1 = 0.f;
#pragma unroll
    for (int e = 0; e < 34; e += 2) {
        const float2 wv = *(const float2*)(w + e);
        a0 = fmaf(z[e + 0], wv.x, a0);
        a1 = fmaf(z[e + 1], wv.y, a1);
    }
    return a0 + a1;
}

// split LayerNorm over 68: each lane holds 36-slice (g0 has 4 zero-pads).
// gam/bet pre-offset by 32*g.
__device__ __forceinline__ void ln68s(float (&v)[36], const int g,
                                      const float* __restrict__ gam,
                                      const float* __restrict__ bet) {
    float s1 = 0.f;
#pragma unroll
    for (int j = 0; j < 36; ++j) s1 += v[j];     // g0 pads are 0: no dup
    s1 += __shfl_xor(s1, 1, 64);
    const float m = s1 * (1.0f / 68.0f);
    float s2 = 0.f;
#pragma unroll
    for (int j = 0; j < 32; ++j) { const float d = v[j] - m; s2 = fmaf(d, d, s2); }
#pragma unroll
    for (int j = 32; j < 36; ++j) { float d = v[j] - m; d = g ? d : 0.f; s2 = fmaf(d, d, s2); }
    s2 += __shfl_xor(s2, 1, 64);
    const float rs = rsqrtf(s2 * (1.0f / 68.0f) + 1e-5f);
#pragma unroll
    for (int j = 0; j < 32; ++j) v[j] = (v[j] - m) * rs * gam[j] + bet[j];
#pragma unroll
    for (int j = 32; j < 36; ++j) {
        const float nv = (v[j] - m) * rs * gam[j] + bet[j];
        v[j] = g ? nv : 0.f;                     // keep g0 pads at zero
    }
}

__global__ void __launch_bounds__(64)
__attribute__((amdgpu_waves_per_eu(3, 8)))
deeparcnet_fused(const float* __restrict__ x,        // [B,6,37,5]
                 const float* __restrict__ conv_w,   // [6,1,5,5]
                 const float* __restrict__ conv_b,   // [6]
                 const float* __restrict__ lemb_w,   // [6,4]
                 const float* __restrict__ lemb_b,   // [6,4]
                 const float* __restrict__ wq,       // [2,2,34,68]
                 const float* __restrict__ wk,
                 const float* __restrict__ wv,
                 const float* __restrict__ proj_w,   // [2,68,68]
                 const float* __restrict__ proj_b,   // [2,68]
                 const float* __restrict__ ff1_w,    // [2,34,68]
                 const float* __restrict__ ff1_b,    // [2,34]
                 const float* __restrict__ ff2_w,    // [2,68,34]
                 const float* __restrict__ ff2_b,    // [2,68]
                 const float* __restrict__ ln1_g, const float* __restrict__ ln1_b,
                 const float* __restrict__ ln2_g, const float* __restrict__ ln2_b,
                 const float* __restrict__ lnf_g, const float* __restrict__ lnf_b,
                 const float* __restrict__ fc_w,     // [6,408]
                 const float* __restrict__ fc_b,     // [6]
                 float* __restrict__ out,            // [B,6]
                 int B)
{
    __shared__ __align__(16) float rowT[36 * ROWW];  // 9936 B

    const int lane = threadIdx.x;        // block = one wave
    const int slot = lane / 12;          // item slot 0..5 (5 = spare lanes)
    const int lin  = lane - slot * 12;
    const int t    = lin >> 1;           // token 0..5
    const int g    = lin & 1;            // e-half: 0 -> [0,32), 1 -> [32,68)
    const int item = blockIdx.x * 5 + slot;
    const bool active = (slot < 5) && (item < B);
    const int it = active ? item : 0;
    const int eo = 32 * g;

    // NOTE: no __restrict__ here -- myR/bas alias (same rows); the
    // streaming write->read ordering depends on the compiler seeing it.
    float* myR = rowT + (lane >> 1) * ROWW;              // my token's row
    const float* bas = rowT + ((lane >> 1) - t) * ROWW;  // item's row base

    // ---------------- conv encode + embed + pos -> h[36] slice -------------
    float h[36];
    {
        float xw[25];
#pragma unroll
        for (int k = 0; k < 25; ++k) xw[k] = conv_w[t * 25 + k];
        const float cb = conv_b[t];
        const float* xp = x + (size_t)(it * 6 + t) * 185;
        const float lw0 = lemb_w[t*4+0], lw1 = lemb_w[t*4+1];
        const float lw2 = lemb_w[t*4+2], lw3 = lemb_w[t*4+3];
        const float lb0 = lemb_b[t*4+0], lb1 = lemb_b[t*4+1];
        const float lb2 = lemb_b[t*4+2], lb3 = lemb_b[t*4+3];
        const int pb = 8 * g;            // g0: positions 0..8, g1: 8..16
#pragma unroll
        for (int tt = 0; tt < 9; ++tt) {
            float a = cb;
#pragma unroll
            for (int k = 0; k < 25; ++k) a = fmaf(xp[(pb + tt) * 10 + k], xw[k], a);
            const float xc = fmaxf(a, 0.0f);
            const float Pf = (float)(pb + tt);
            float v0 = fmaf(xc, lw0, lb0) + __sinf(Pf);
            float v1 = fmaf(xc, lw1, lb1) + __sinf(Pf * (1.0f / 18.0f));
            float v2 = fmaf(xc, lw2, lb2) + __cosf(Pf);
            float v3 = fmaf(xc, lw3, lb3) + __cosf(Pf * (1.0f / 18.0f));
            if (tt == 8) {               // g0's slots 32..35 must stay 0
                v0 = g ? v0 : 0.f; v1 = g ? v1 : 0.f;
                v2 = g ? v2 : 0.f; v3 = g ? v3 : 0.f;
            }
            h[4*tt+0] = v0; h[4*tt+1] = v1; h[4*tt+2] = v2; h[4*tt+3] = v3;
        }
    }

    const float qscale = 0.16903085094570331f;  // 34^-0.5

#pragma unroll 1
    for (int l = 0; l < 2; ++l) {
        const float* Wq = wq + l * 4624;
        const float* Wk = wk + l * 4624;
        const float* Wv = wv + l * 4624;
        const float* Pw = proj_w + l * 4624;
        const float* Pb = proj_b + l * 68;
        const float* W1 = ff1_w + l * 2312;
        const float* b1 = ff1_b + l * 34;
        const float* W2 = ff2_w + l * 2312;
        const float* b2 = ff2_b + l * 68;
        const float* lgm1 = ln1_g + l * 68 + eo; const float* lbt1 = ln1_b + l * 68 + eo;
        const float* lgm2 = ln2_g + l * 68 + eo; const float* lbt2 = ln2_b + l * 68 + eo;

        float attn_own[34];              // my head's (head g) attn dims
#pragma unroll
        for (int d = 0; d < 34; ++d) attn_own[d] = 0.f;

        // ---- per head: streamed QKV + scores, softmax, V-gather ----
#pragma unroll 1
        for (int hh = 0; hh < 2; ++hh) {
            const float* WQh = Wq + hh * 2312 + eo;
            const float* WKh = Wk + hh * 2312 + eo;
            const float* WVh = Wv + hh * 2312 + eo;
            float sc[6];
#pragma unroll
            for (int s = 0; s < 6; ++s) sc[s] = 0.f;

#pragma unroll 1
            for (int d = 0; d < 34; ++d) {
                const float kd = dot36g(h, WKh + d * 68);
                const float kf = kd + __shfl_xor(kd, 1, 64);
                if (!g) myR[64] = kf;                     // k exchange slot
                const float qd = dot36g(h, WQh + d * 68);
                const float qf = qd + __shfl_xor(qd, 1, 64);
                const float vd = dot36g(h, WVh + d * 68);
                const float vf = vd + __shfl_xor(vd, 1, 64);
                if ((d >= 17) == (g != 0)) myR[d] = vf;   // v row, split write
#pragma unroll
                for (int s = 0; s < 6; ++s)
                    sc[s] = fmaf(qf, bas[s * ROWW + 64], sc[s]);
            }

            // softmax (q-scale folded); both pair lanes identical
            float m = sc[0] * qscale;
#pragma unroll
            for (int s = 0; s < 6; ++s) { sc[s] *= qscale; m = fmaxf(m, sc[s]); }
            float sum = 0.f;
#pragma unroll
            for (int s = 0; s < 6; ++s) { sc[s] = __expf(sc[s] - m); sum += sc[s]; }
            const float r = 1.0f / sum;
#pragma unroll
            for (int s = 0; s < 6; ++s) sc[s] *= r;

            // V-gather for head hh -> rowT[35+d] (rolled; LDS sink)
#pragma unroll 1
            for (int d = 0; d < 34; ++d) {
                float a = sc[0] * bas[0 * ROWW + d];
                a = fmaf(sc[1], bas[1 * ROWW + d], a);
                a = fmaf(sc[2], bas[2 * ROWW + d], a);
                a = fmaf(sc[3], bas[3 * ROWW + d], a);
                a = fmaf(sc[4], bas[4 * ROWW + d], a);
                a = fmaf(sc[5], bas[5 * ROWW + d], a);
                if (!g) myR[35 + d] = a;
            }
            // keep into registers iff this is my head (compile-time d)
#pragma unroll
            for (int d = 0; d < 34; ++d) {
                const float gv = myR[35 + d];
                attn_own[d] = (hh == g) ? gv : attn_own[d];
            }
        }

        // ---- rebuild aligned e-layout: g0 [attn0..31,0x4]; g1 [a32,a33,attn0..33]
        const float a32 = __shfl_xor(attn_own[32], 1, 64);
        const float a33 = __shfl_xor(attn_own[33], 1, 64);
        float av[36];
        av[0] = g ? a32 : attn_own[0];
        av[1] = g ? a33 : attn_own[1];
#pragma unroll
        for (int j = 2; j < 32; ++j) av[j] = g ? attn_own[j - 2] : attn_own[j];
#pragma unroll
        for (int j = 32; j < 36; ++j) av[j] = g ? attn_own[j - 2] : 0.f;

        // ---- proj: pass1 partials for partner's p-range -> rowT ----
        const int po = 32 - eo;          // partner's output base
#pragma unroll 1
        for (int j = 0; j < 36; ++j) {
            const int p = po + j;
            const float part = dot36g(av, Pw + p * 68 + eo);
            if (!g || j < 32) myR[p] = part;   // g1's targets valid j<32 only
        }
        // pass2: own range = partner partial + own partial + bias
#pragma unroll 1
        for (int j = 0; j < 36; ++j) {
            const int p = eo + j;
            const float yv = myR[p] + dot36g(av, Pw + p * 68 + eo) + Pb[p];
            if (g || j < 32) myR[p] = yv;
        }
        // residual (keep g0 pads zero)
#pragma unroll
        for (int j = 0; j < 32; ++j) h[j] += myR[eo + j];
#pragma unroll
        for (int j = 32; j < 36; ++j) h[j] += g ? myR[eo + j] : 0.f;
        ln68s(h, g, lgm1, lbt1);

        // ---- ff1: partial + combine -> z (full 34 on both lanes) ----
#pragma unroll 1
        for (int f = 0; f < 34; ++f) {
            const float zp = dot36g(h, W1 + f * 68 + eo);
            const float zf = zp + __shfl_xor(zp, 1, 64);
            if (!g) myR[f] = fmaxf(zf + b1[f], 0.f);
        }
        float z[34];
#pragma unroll
        for (int f = 0; f < 34; ++f) z[f] = myR[f];

        // ---- ff2: own-half outputs, full-depth dots ----
#pragma unroll 1
        for (int j = 0; j < 36; ++j) {
            const int p = eo + j;
            const float yv = dot34g2(z, W2 + p * 34) + b2[p];
            if (g || j < 32) myR[p] = yv;
        }
#pragma unroll
        for (int j = 0; j < 32; ++j) h[j] += myR[eo + j];
#pragma unroll
        for (int j = 32; j < 36; ++j) h[j] += g ? myR[eo + j] : 0.f;
        ln68s(h, g, lgm2, lbt2);
    }

    // ---------------- final LN ----------------
    ln68s(h, g, lnf_g + eo, lnf_b + eo);

    // ---------------- fc head ----------------
    float p6[6];
#pragma unroll
    for (int o = 0; o < 6; ++o) {
        const float pp = dot36g(h, fc_w + o * 408 + t * 68 + eo);
        p6[o] = pp + __shfl_xor(pp, 1, 64);   // full token contribution
    }
    const int base_lane = slot * 12;
    float tot[6];
#pragma unroll
    for (int o = 0; o < 6; ++o) {
        float a = 0.f;
#pragma unroll
        for (int s = 0; s < 6; ++s) a += __shfl(p6[o], base_lane + 2 * s, 64);
        tot[o] = a + fc_b[o];
    }
    float myout = tot[0];
    if (t == 1) myout = tot[1];
    if (t == 2) myout = tot[2];
    if (t == 3) myout = tot[3];
    if (t == 4) myout = tot[4];
    if (t == 5) myout = tot[5];
    if (active && g == 0) out[(size_t)item * 6 + t] = fmaxf(myout, 0.f);
}

extern "C" void kernel_launch(void* const* d_in, const int* in_sizes, int n_in,
                              void* d_out, int out_size, void* d_ws, size_t ws_size,
                              hipStream_t stream) {
    const float* x      = (const float*)d_in[0];
    const float* conv_w = (const float*)d_in[1];
    const float* conv_b = (const float*)d_in[2];
    const float* lemb_w = (const float*)d_in[3];
    const float* lemb_b = (const float*)d_in[4];
    const float* wq     = (const float*)d_in[5];
    const float* wk     = (const float*)d_in[6];
    const float* wv     = (const float*)d_in[7];
    const float* proj_w = (const float*)d_in[8];
    const float* proj_b = (const float*)d_in[9];
    const float* ff1_w  = (const float*)d_in[10];
    const float* ff1_b  = (const float*)d_in[11];
    const float* ff2_w  = (const float*)d_in[12];
    const float* ff2_b  = (const float*)d_in[13];
    const float* ln1_g  = (const float*)d_in[14];
    const float* ln1_b  = (const float*)d_in[15];
    const float* ln2_g  = (const float*)d_in[16];
    const float* ln2_b  = (const float*)d_in[17];
    const float* lnf_g  = (const float*)d_in[18];
    const float* lnf_b  = (const float*)d_in[19];
    const float* fc_w   = (const float*)d_in[20];
    const float* fc_b   = (const float*)d_in[21];
    float* out = (float*)d_out;

    const int B = in_sizes[0] / (6 * 37 * 5);           // 32768
    const int blocks = (B + 4) / 5;                     // 5 items per wave
    deeparcnet_fused<<<blocks, 64, 0, stream>>>(
        x, conv_w, conv_b, lemb_w, lemb_b, wq, wk, wv, proj_w, proj_b,
        ff1_w, ff1_b, ff2_w, ff2_b, ln1_g, ln1_b, ln2_g, ln2_b,
        lnf_g, lnf_b, fc_w, fc_b, out, B);
}

// Round 6
// 2330.436 us; speedup vs baseline: 1.1616x; 1.1616x over previous
//
#include <hip/hip_runtime.h>
#include <math.h>

// DeepArcNet fused kernel, R11b: identical to R11 (bench never ran --
// GPUAcquisitionTimeout again; resubmitting unmodified for a clean
// measurement).
// R10 post-mortem: waves_per_eu(3,8) forced VGPR=84 -> spills (WRITE 23MB);
// streamed k-exchange = per-iteration LDS write->read WAR chain (no overlap
// possible); 5M bank conflicts. Reverted entirely.
// Arithmetic that picks this design: FMA-issue floor ~130us; LDS-broadcast
// weights (R7/R8) cost 4B/lane-MAC = 38GB LDS traffic = ~550us floor ->
// that structure is dead. R9 killed the LDS pipe but the compiler proved
// weight addresses uniform and emitted s_load (out-of-order returns ->
// lgkmcnt(0) full drain per use -> serialized, VALUBusy 10%).
// R11 fix: opaque VGPR zero (inline-asm v_mov) added to every hot weight/
// bias pointer -> addresses are VGPR-based -> global_load_dwordx4: in-order,
// vmcnt-counted, deeply compiler-pipelined (R7 proved this pipelines at
// VALUBusy 40%). Panels are L1-resident (<=18.5KB); uniform-address loads
// broadcast one line to all lanes. 4-wave blocks (R7's dispatch shape:
// 17.8% occ vs 10.8% for 1-wave blocks). LDS only for the intra-wave k/v
// row exchange (proven, 0 conflicts). Rule-20 discipline unchanged.

#define EMBD 68
#define NTOK 6
#define HEADD 34
#define LDSW 35                    // 34 slots + 1 pad (2-way banks = free)

// dot of register vector h[68] with weight row w (vector-load path)
__device__ __forceinline__ float dot68v(const float (&h)[EMBD],
                                        const float* w) {
    float a0 = 0.f, a1 = 0.f, a2 = 0.f, a3 = 0.f;
#pragma unroll
    for (int e = 0; e < EMBD; e += 4) {
        const float4 wv = *(const float4*)(w + e);
        a0 = fmaf(h[e + 0], wv.x, a0);
        a1 = fmaf(h[e + 1], wv.y, a1);
        a2 = fmaf(h[e + 2], wv.z, a2);
        a3 = fmaf(h[e + 3], wv.w, a3);
    }
    return (a0 + a1) + (a2 + a3);
}

__device__ __forceinline__ float dot34v(const float (&z)[HEADD],
                                        const float* w) {
    float a0 = 0.f, a1 = 0.f;
#pragma unroll
    for (int e = 0; e < HEADD; e += 2) {
        const float2 wv = *(const float2*)(w + e);
        a0 = fmaf(z[e + 0], wv.x, a0);
        a1 = fmaf(z[e + 1], wv.y, a1);
    }
    return a0 + a1;
}

__device__ __forceinline__ void ln68_ip(float (&v)[EMBD],
                                        const float* g,
                                        const float* b) {
    float s1 = 0.f;
#pragma unroll
    for (int e = 0; e < EMBD; ++e) s1 += v[e];
    const float m = s1 * (1.0f / 68.0f);
    float s2 = 0.f;
#pragma unroll
    for (int e = 0; e < EMBD; ++e) { const float d = v[e] - m; s2 = fmaf(d, d, s2); }
    const float rs = rsqrtf(s2 * (1.0f / 68.0f) + 1e-5f);
#pragma unroll
    for (int e = 0; e < EMBD; ++e) v[e] = (v[e] - m) * rs * g[e] + b[e];
}

__global__ void __launch_bounds__(256, 1)
__attribute__((amdgpu_waves_per_eu(1, 2)))
deeparcnet_fused(const float* __restrict__ x,        // [B,6,37,5]
                 const float* __restrict__ conv_w,   // [6,1,5,5]
                 const float* __restrict__ conv_b,   // [6]
                 const float* __restrict__ lemb_w,   // [6,4]
                 const float* __restrict__ lemb_b,   // [6,4]
                 const float* __restrict__ wq,       // [2,2,34,68]
                 const float* __restrict__ wk,
                 const float* __restrict__ wv,
                 const float* __restrict__ proj_w,   // [2,68,68]
                 const float* __restrict__ proj_b,   // [2,68]
                 const float* __restrict__ ff1_w,    // [2,34,68]
                 const float* __restrict__ ff1_b,    // [2,34]
                 const float* __restrict__ ff2_w,    // [2,68,34]
                 const float* __restrict__ ff2_b,    // [2,68]
                 const float* __restrict__ ln1_g, const float* __restrict__ ln1_b,
                 const float* __restrict__ ln2_g, const float* __restrict__ ln2_b,
                 const float* __restrict__ lnf_g, const float* __restrict__ lnf_b,
                 const float* __restrict__ fc_w,     // [6,408]
                 const float* __restrict__ fc_b,     // [6]
                 float* __restrict__ out,            // [B,6]
                 int B)
{
    __shared__ __align__(16) float rows[256 * LDSW];  // 35840 B

    const int tid  = threadIdx.x;
    const int lane = tid & 63;
    const int wid  = blockIdx.x * 4 + (tid >> 6);
    const int sub  = lane / 6;          // item slot in wave: 0..10
    const int c    = lane - sub * 6;    // token / conv channel: 0..5
    const int item = wid * 10 + sub;
    const bool active = (sub < 10) && (item < B);
    const int it = active ? item : 0;

    // Opaque zero the compiler cannot fold: defeats address-uniformity
    // scalarization (R9's s_load trap) -> forces global_load vector path.
    int vzero;
    asm volatile("v_mov_b32 %0, 0" : "=v"(vzero));

    const float* wq_v  = wq     + vzero;
    const float* wk_v  = wk     + vzero;
    const float* wv_v  = wv     + vzero;
    const float* pw_v  = proj_w + vzero;
    const float* pb_v  = proj_b + vzero;
    const float* w1_v  = ff1_w  + vzero;
    const float* b1_v  = ff1_b  + vzero;
    const float* w2_v  = ff2_w  + vzero;
    const float* b2_v  = ff2_b  + vzero;
    const float* l1g_v = ln1_g  + vzero;
    const float* l1b_v = ln1_b  + vzero;
    const float* l2g_v = ln2_g  + vzero;
    const float* l2b_v = ln2_b  + vzero;
    const float* lfg_v = lnf_g  + vzero;
    const float* lfb_v = lnf_b  + vzero;

    // myrow/grow intentionally NOT __restrict__: they alias within the wave
    // and the k/v produce->consume ordering must stay visible.
    float* myrow = rows + tid * LDSW;            // lane-private
    const float* grow = rows + (tid - c) * LDSW; // item's 6-row base

    // ---------------- conv encode + embed + pos -> h[68] -------------------
    float h[EMBD];
    {
        float xw[25];
#pragma unroll
        for (int k = 0; k < 25; ++k) xw[k] = conv_w[c * 25 + k];
        const float cb = conv_b[c];
        const float* xp = x + (size_t)(it * 6 + c) * 185;

        const float lw0 = lemb_w[c * 4 + 0], lw1 = lemb_w[c * 4 + 1];
        const float lw2 = lemb_w[c * 4 + 2], lw3 = lemb_w[c * 4 + 3];
        const float lb0 = lemb_b[c * 4 + 0], lb1 = lemb_b[c * 4 + 1];
        const float lb2 = lemb_b[c * 4 + 2], lb3 = lemb_b[c * 4 + 3];

#pragma unroll
        for (int t = 0; t < 17; ++t) {
            float a = cb;
#pragma unroll
            for (int k = 0; k < 25; ++k) a = fmaf(xp[t * 10 + k], xw[k], a);
            const float xc = fmaxf(a, 0.0f);
            const float tf = (float)t;
            h[4 * t + 0] = fmaf(xc, lw0, lb0) + __sinf(tf);
            h[4 * t + 1] = fmaf(xc, lw1, lb1) + __sinf(tf * (1.0f / 18.0f));
            h[4 * t + 2] = fmaf(xc, lw2, lb2) + __cosf(tf);
            h[4 * t + 3] = fmaf(xc, lw3, lb3) + __cosf(tf * (1.0f / 18.0f));
        }
    }

    const float qscale = 0.16903085094570331f;  // 34^-0.5

#pragma unroll 1
    for (int l = 0; l < 2; ++l) {
        const float* Wq = wq_v + l * (2 * HEADD * EMBD);
        const float* Wk = wk_v + l * (2 * HEADD * EMBD);
        const float* Wv = wv_v + l * (2 * HEADD * EMBD);
        const float* Pw = pw_v + l * (EMBD * EMBD);
        const float* Pb = pb_v + l * EMBD;
        const float* W1 = w1_v + l * (HEADD * EMBD);
        const float* b1 = b1_v + l * HEADD;
        const float* W2 = w2_v + l * (EMBD * HEADD);
        const float* b2 = b2_v + l * EMBD;
        const float* g1 = l1g_v + l * EMBD; const float* e1 = l1b_v + l * EMBD;
        const float* g2 = l2g_v + l * EMBD; const float* e2 = l2b_v + l * EMBD;

        // ---- scores, per head: k rows -> LDS, q streamed, wei in regs ----
        // hh fully unrolled (compile-time wei index); d loops rolled
        // (write only LDS myrow / accumulators).
        float wei[2][NTOK];
#pragma unroll
        for (int hh = 0; hh < 2; ++hh) {
            const float* WKh = Wk + hh * HEADD * EMBD;
            const float* WQh = Wq + hh * HEADD * EMBD;

#pragma unroll 2
            for (int d = 0; d < HEADD; ++d)
                myrow[d] = dot68v(h, WKh + d * EMBD);

            float w0 = 0.f, w1 = 0.f, w2 = 0.f, w3 = 0.f, w4 = 0.f, w5 = 0.f;
#pragma unroll 2
            for (int d = 0; d < HEADD; ++d) {
                const float qd = dot68v(h, WQh + d * EMBD);
                w0 = fmaf(qd, grow[0 * LDSW + d], w0);
                w1 = fmaf(qd, grow[1 * LDSW + d], w1);
                w2 = fmaf(qd, grow[2 * LDSW + d], w2);
                w3 = fmaf(qd, grow[3 * LDSW + d], w3);
                w4 = fmaf(qd, grow[4 * LDSW + d], w4);
                w5 = fmaf(qd, grow[5 * LDSW + d], w5);
            }
            wei[hh][0] = w0; wei[hh][1] = w1; wei[hh][2] = w2;
            wei[hh][3] = w3; wei[hh][4] = w4; wei[hh][5] = w5;
        }

        // ---- softmax (q-scale folded) ----
#pragma unroll
        for (int hh = 0; hh < 2; ++hh) {
            float m = wei[hh][0] * qscale;
#pragma unroll
            for (int s = 0; s < NTOK; ++s) { wei[hh][s] *= qscale; m = fmaxf(m, wei[hh][s]); }
            float sum = 0.f;
#pragma unroll
            for (int s = 0; s < NTOK; ++s) { wei[hh][s] = __expf(wei[hh][s] - m); sum += wei[hh][s]; }
            const float r = 1.0f / sum;
#pragma unroll
            for (int s = 0; s < NTOK; ++s) wei[hh][s] *= r;
        }

        // ---- attn: v rows -> LDS, gather (attn compile-time indexed) ----
        float attn[EMBD];
#pragma unroll
        for (int hh = 0; hh < 2; ++hh) {
            const float* WVh = Wv + hh * HEADD * EMBD;
#pragma unroll 2
            for (int d = 0; d < HEADD; ++d)
                myrow[d] = dot68v(h, WVh + d * EMBD);
#pragma unroll
            for (int d = 0; d < HEADD; ++d) {
                float a = wei[hh][0] * grow[0 * LDSW + d];
                a = fmaf(wei[hh][1], grow[1 * LDSW + d], a);
                a = fmaf(wei[hh][2], grow[2 * LDSW + d], a);
                a = fmaf(wei[hh][3], grow[3 * LDSW + d], a);
                a = fmaf(wei[hh][4], grow[4 * LDSW + d], a);
                a = fmaf(wei[hh][5], grow[5 * LDSW + d], a);
                attn[hh * HEADD + d] = a;
            }
        }

        // ---- proj + residual (q2 unrolled: compile-time h index) ----
#pragma unroll
        for (int q2 = 0; q2 < 2; ++q2) {
#pragma unroll 2
            for (int p = 0; p < HEADD; ++p)
                myrow[p] = Pb[q2 * HEADD + p] + dot68v(attn, Pw + (q2 * HEADD + p) * EMBD);
#pragma unroll
            for (int p = 0; p < HEADD; ++p) h[q2 * HEADD + p] += myrow[p];
        }
        ln68_ip(h, g1, e1);

        // ---- ff1 (roundtrip via myrow -> z regs) + ff2 ----
#pragma unroll 2
        for (int f = 0; f < HEADD; ++f)
            myrow[f] = fmaxf(b1[f] + dot68v(h, W1 + f * EMBD), 0.f);
        float z[HEADD];
#pragma unroll
        for (int f = 0; f < HEADD; ++f) z[f] = myrow[f];

#pragma unroll
        for (int q2 = 0; q2 < 2; ++q2) {
#pragma unroll 2
            for (int p = 0; p < HEADD; ++p)
                myrow[p] = b2[q2 * HEADD + p] + dot34v(z, W2 + (q2 * HEADD + p) * HEADD);
#pragma unroll
            for (int p = 0; p < HEADD; ++p) h[q2 * HEADD + p] += myrow[p];
        }
        ln68_ip(h, g2, e2);
    }

    // ---------------- final LN ----------------
    ln68_ip(h, lfg_v, lfb_v);

    // ---------------- fc head (per-lane slices, L1-resident 10KB) ----------
    const int base_lane = sub * 6;
    float p[NTOK];
#pragma unroll
    for (int o = 0; o < NTOK; ++o)
        p[o] = dot68v(h, fc_w + o * 408 + c * EMBD);

    float tot[NTOK];
#pragma unroll
    for (int o = 0; o < NTOK; ++o) {
        float a = 0.f;
#pragma unroll
        for (int t = 0; t < NTOK; ++t) a += __shfl(p[o], base_lane + t, 64);
        tot[o] = a + fc_b[o];
    }
    float myout = tot[0];
    if (c == 1) myout = tot[1];
    if (c == 2) myout = tot[2];
    if (c == 3) myout = tot[3];
    if (c == 4) myout = tot[4];
    if (c == 5) myout = tot[5];
    if (active) out[(size_t)item * 6 + c] = fmaxf(myout, 0.f);
}

extern "C" void kernel_launch(void* const* d_in, const int* in_sizes, int n_in,
                              void* d_out, int out_size, void* d_ws, size_t ws_size,
                              hipStream_t stream) {
    const float* x      = (const float*)d_in[0];
    const float* conv_w = (const float*)d_in[1];
    const float* conv_b = (const float*)d_in[2];
    const float* lemb_w = (const float*)d_in[3];
    const float* lemb_b = (const float*)d_in[4];
    const float* wq     = (const float*)d_in[5];
    const float* wk     = (const float*)d_in[6];
    const float* wv     = (const float*)d_in[7];
    const float* proj_w = (const float*)d_in[8];
    const float* proj_b = (const float*)d_in[9];
    const float* ff1_w  = (const float*)d_in[10];
    const float* ff1_b  = (const float*)d_in[11];
    const float* ff2_w  = (const float*)d_in[12];
    const float* ff2_b  = (const float*)d_in[13];
    const float* ln1_g  = (const float*)d_in[14];
    const float* ln1_b  = (const float*)d_in[15];
    const float* ln2_g  = (const float*)d_in[16];
    const float* ln2_b  = (const float*)d_in[17];
    const float* lnf_g  = (const float*)d_in[18];
    const float* lnf_b  = (const float*)d_in[19];
    const float* fc_w   = (const float*)d_in[20];
    const float* fc_b   = (const float*)d_in[21];
    float* out = (float*)d_out;

    const int B = in_sizes[0] / (6 * 37 * 5);           // 32768
    const int waves  = (B + 9) / 10;                    // 10 items per wave
    const int blocks = (waves + 3) / 4;                 // 4 waves per block

    deeparcnet_fused<<<blocks, 256, 0, stream>>>(
        x, conv_w, conv_b, lemb_w, lemb_b, wq, wk, wv, proj_w, proj_b,
        ff1_w, ff1_b, ff2_w, ff2_b, ln1_g, ln1_b, ln2_g, ln2_b,
        lnf_g, lnf_b, fc_w, fc_b, out, B);
}

// Round 7
// 1610.268 us; speedup vs baseline: 1.6811x; 1.4472x over previous
//
#include <hip/hip_runtime.h>
#include <math.h>

// DeepArcNet fused kernel, R12: LDS-broadcast weights + split-lane state.
// Evidence across R7-R11: perf is MONOTONE IN OCCUPANCY, not weight-path
// (R7 vgpr120/occ17.8/1054 > R8 248/9.8/1430 > R9 s_load 1617 > R11 forced
// global 2330). Latency-bound: only resident-wave count matters.
// R12 = R8's proven phase dataflow (stage panel -> barrier -> broadcast
// ds_read dots; k/v via intra-wave rows; NO streamed WAR chain) + R10's
// half-token layout (2 lanes/token, h[36], 16B-aligned e-halves) to cut
// per-lane state ~2x. R10's failure modes removed: waves_per_eu PINNED
// (3,3) (170-reg budget, no forced spill -- R10's (3,8) made the allocator
// chase 8/EU and spill at 84); no per-d k-exchange; stride-35 rows.
// New: proj iterates FULL p 0..67 unrolled so shfl_xor pairs partials of
// the SAME p (fixes R10's mismatch) with compile-time predicated h updates;
// gather computed redundantly by both pair lanes straight into registers;
// ff2 needs no exchange (z replicated). LDS 38.7KB -> 4 blocks/CU; 5
// items/wave -> 6556 waves; 12 waves/CU resident (2.1x R7).

#define NTOK 6
#define ROWW 35                    // 34 k/v slots + 1 pad
#define WBUF 4624                  // max staged panel: 68x68 floats

// dot of 36-elem register half with 16B-aligned LDS row slice (broadcast:
// all lanes same addr, or 2 addrs for the g0/g1 halves -- 2-way is free)
__device__ __forceinline__ float dot36(const float (&h)[36], const float* w) {
    float a0 = 0.f, a1 = 0.f, a2 = 0.f, a3 = 0.f;
#pragma unroll
    for (int e = 0; e < 36; e += 4) {
        const float4 wv = *(const float4*)(w + e);
        a0 = fmaf(h[e + 0], wv.x, a0);
        a1 = fmaf(h[e + 1], wv.y, a1);
        a2 = fmaf(h[e + 2], wv.z, a2);
        a3 = fmaf(h[e + 3], wv.w, a3);
    }
    return (a0 + a1) + (a2 + a3);
}

__device__ __forceinline__ float dot34(const float (&z)[34], const float* w) {
    float a0 = 0.f, a1 = 0.f;
#pragma unroll
    for (int e = 0; e < 34; e += 2) {
        const float2 wv = *(const float2*)(w + e);
        a0 = fmaf(z[e + 0], wv.x, a0);
        a1 = fmaf(z[e + 1], wv.y, a1);
    }
    return a0 + a1;
}

// split LayerNorm over 68: lane holds 36-slice (g0 has 4 zero pads).
// gam/bet pre-offset by 32*g.  (verbatim from R10 -- harness-passed)
__device__ __forceinline__ void ln68s(float (&v)[36], const int g,
                                      const float* gam, const float* bet) {
    float s1 = 0.f;
#pragma unroll
    for (int j = 0; j < 36; ++j) s1 += v[j];
    s1 += __shfl_xor(s1, 1, 64);
    const float m = s1 * (1.0f / 68.0f);
    float s2 = 0.f;
#pragma unroll
    for (int j = 0; j < 32; ++j) { const float d = v[j] - m; s2 = fmaf(d, d, s2); }
#pragma unroll
    for (int j = 32; j < 36; ++j) { float d = v[j] - m; d = g ? d : 0.f; s2 = fmaf(d, d, s2); }
    s2 += __shfl_xor(s2, 1, 64);
    const float rs = rsqrtf(s2 * (1.0f / 68.0f) + 1e-5f);
#pragma unroll
    for (int j = 0; j < 32; ++j) v[j] = (v[j] - m) * rs * gam[j] + bet[j];
#pragma unroll
    for (int j = 32; j < 36; ++j) {
        const float nv = (v[j] - m) * rs * gam[j] + bet[j];
        v[j] = g ? nv : 0.f;
    }
}

#define STAGE1(SRC, N4)                                                     \
    do {                                                                    \
        __syncthreads();                                                    \
        {                                                                   \
            float4* d4 = (float4*)wbuf;                                     \
            const float4* s4 = (const float4*)(SRC);                        \
            for (int i = tid; i < (N4); i += 256) d4[i] = s4[i];            \
        }                                                                   \
        __syncthreads();                                                    \
    } while (0)

#define STAGE2(SRCA, SRCB, N4)                                              \
    do {                                                                    \
        __syncthreads();                                                    \
        {                                                                   \
            float4* d4 = (float4*)wbuf;                                     \
            const float4* a4 = (const float4*)(SRCA);                       \
            const float4* b4 = (const float4*)(SRCB);                       \
            for (int i = tid; i < (N4); i += 256) d4[i] = a4[i];            \
            for (int i = tid; i < (N4); i += 256) d4[(N4) + i] = b4[i];     \
        }                                                                   \
        __syncthreads();                                                    \
    } while (0)

__global__ void __launch_bounds__(256)
__attribute__((amdgpu_waves_per_eu(3, 3)))
deeparcnet_fused(const float* __restrict__ x,        // [B,6,37,5]
                 const float* __restrict__ conv_w,   // [6,1,5,5]
                 const float* __restrict__ conv_b,   // [6]
                 const float* __restrict__ lemb_w,   // [6,4]
                 const float* __restrict__ lemb_b,   // [6,4]
                 const float* __restrict__ wq,       // [2,2,34,68]
                 const float* __restrict__ wk,
                 const float* __restrict__ wv,
                 const float* __restrict__ proj_w,   // [2,68,68]
                 const float* __restrict__ proj_b,   // [2,68]
                 const float* __restrict__ ff1_w,    // [2,34,68]
                 const float* __restrict__ ff1_b,    // [2,34]
                 const float* __restrict__ ff2_w,    // [2,68,34]
                 const float* __restrict__ ff2_b,    // [2,68]
                 const float* __restrict__ ln1_g, const float* __restrict__ ln1_b,
                 const float* __restrict__ ln2_g, const float* __restrict__ ln2_b,
                 const float* __restrict__ lnf_g, const float* __restrict__ lnf_b,
                 const float* __restrict__ fc_w,     // [6,408]
                 const float* __restrict__ fc_b,     // [6]
                 float* __restrict__ out,            // [B,6]
                 int B)
{
    __shared__ __align__(16) float rows[144 * ROWW];  // 4 waves x 36 rows
    __shared__ __align__(16) float wbuf[WBUF];

    const int tid  = threadIdx.x;
    const int wvi  = tid >> 6;
    const int lane = tid & 63;
    const int slot = lane / 12;          // item slot 0..5 (5 = spare)
    const int lin  = lane - slot * 12;
    const int t    = lin >> 1;           // token 0..5
    const int g    = lin & 1;            // e-half: 0 -> [0,32), 1 -> [32,68)
    const int item = (blockIdx.x * 4 + wvi) * 5 + slot;
    const bool active = (slot < 5) && (item < B);
    const int it = active ? item : 0;
    const int eo = 32 * g;

    // one row per TOKEN (pair lanes share); no __restrict__ (rows alias,
    // produce->consume ordering must stay visible to the compiler).
    float* myrow = rows + (wvi * 36 + slot * 6 + t) * ROWW;
    const float* bas = rows + (wvi * 36 + slot * 6) * ROWW;

    // ---------------- conv encode + embed + pos -> h[36] half --------------
    float h[36];
    {
        float xw[25];
#pragma unroll
        for (int k = 0; k < 25; ++k) xw[k] = conv_w[t * 25 + k];
        const float cb = conv_b[t];
        const float* xp = x + (size_t)(it * 6 + t) * 185;
        const float lw0 = lemb_w[t*4+0], lw1 = lemb_w[t*4+1];
        const float lw2 = lemb_w[t*4+2], lw3 = lemb_w[t*4+3];
        const float lb0 = lemb_b[t*4+0], lb1 = lemb_b[t*4+1];
        const float lb2 = lemb_b[t*4+2], lb3 = lemb_b[t*4+3];
        const int pb = 8 * g;            // g0: positions 0..8, g1: 8..16
#pragma unroll
        for (int tt = 0; tt < 9; ++tt) {
            float a = cb;
#pragma unroll
            for (int k = 0; k < 25; ++k) a = fmaf(xp[(pb + tt) * 10 + k], xw[k], a);
            const float xc = fmaxf(a, 0.0f);
            const float Pf = (float)(pb + tt);
            float v0 = fmaf(xc, lw0, lb0) + __sinf(Pf);
            float v1 = fmaf(xc, lw1, lb1) + __sinf(Pf * (1.0f / 18.0f));
            float v2 = fmaf(xc, lw2, lb2) + __cosf(Pf);
            float v3 = fmaf(xc, lw3, lb3) + __cosf(Pf * (1.0f / 18.0f));
            if (tt == 8) {               // g0 slots 32..35 stay 0
                v0 = g ? v0 : 0.f; v1 = g ? v1 : 0.f;
                v2 = g ? v2 : 0.f; v3 = g ? v3 : 0.f;
            }
            h[4*tt+0] = v0; h[4*tt+1] = v1; h[4*tt+2] = v2; h[4*tt+3] = v3;
        }
    }

    const float qscale = 0.16903085094570331f;  // 34^-0.5

#pragma unroll 1
    for (int l = 0; l < 2; ++l) {
        const float* Wq = wq + l * 4624;
        const float* Wk = wk + l * 4624;
        const float* Wv = wv + l * 4624;
        const float* Pw = proj_w + l * 4624;
        const float* Pb = proj_b + l * 68;
        const float* W1 = ff1_w + l * 2312;
        const float* b1 = ff1_b + l * 34;
        const float* W2 = ff2_w + l * 2312;
        const float* b2 = ff2_b + l * 68;
        const float* g1p = ln1_g + l * 68 + eo; const float* e1p = ln1_b + l * 68 + eo;
        const float* g2p = ln2_g + l * 68 + eo; const float* e2p = ln2_b + l * 68 + eo;

        // ---- scores per head: stage Wq_h|Wk_h; k rows -> LDS; q streamed --
        float wei[2][NTOK];
#pragma unroll
        for (int hh = 0; hh < 2; ++hh) {
            STAGE2(Wq + hh * 2312, Wk + hh * 2312, 578);
#pragma unroll 2
            for (int d = 0; d < 34; ++d) {
                const float kp = dot36(h, wbuf + 2312 + d * 68 + eo);
                const float kf = kp + __shfl_xor(kp, 1, 64);
                if (!g) myrow[d] = kf;
            }
            float w0 = 0.f, w1 = 0.f, w2 = 0.f, w3 = 0.f, w4 = 0.f, w5 = 0.f;
#pragma unroll 2
            for (int d = 0; d < 34; ++d) {
                const float qp = dot36(h, wbuf + d * 68 + eo);
                const float qf = qp + __shfl_xor(qp, 1, 64);
                w0 = fmaf(qf, bas[0 * ROWW + d], w0);
                w1 = fmaf(qf, bas[1 * ROWW + d], w1);
                w2 = fmaf(qf, bas[2 * ROWW + d], w2);
                w3 = fmaf(qf, bas[3 * ROWW + d], w3);
                w4 = fmaf(qf, bas[4 * ROWW + d], w4);
                w5 = fmaf(qf, bas[5 * ROWW + d], w5);
            }
            wei[hh][0] = w0; wei[hh][1] = w1; wei[hh][2] = w2;
            wei[hh][3] = w3; wei[hh][4] = w4; wei[hh][5] = w5;
        }

        // ---- softmax (q-scale folded); identical on pair lanes ----
#pragma unroll
        for (int hh = 0; hh < 2; ++hh) {
            float m = wei[hh][0] * qscale;
#pragma unroll
            for (int s = 0; s < NTOK; ++s) { wei[hh][s] *= qscale; m = fmaxf(m, wei[hh][s]); }
            float sum = 0.f;
#pragma unroll
            for (int s = 0; s < NTOK; ++s) { wei[hh][s] = __expf(wei[hh][s] - m); sum += wei[hh][s]; }
            const float r = 1.0f / sum;
#pragma unroll
            for (int s = 0; s < NTOK; ++s) wei[hh][s] *= r;
        }

        // ---- attn: stage Wv (both heads); v rows -> LDS; gather to regs ---
        STAGE2(Wv, Wv + 2312, 578);
        float attn_own[34];              // my head's (head g) attn dims
#pragma unroll
        for (int d = 0; d < 34; ++d) attn_own[d] = 0.f;
#pragma unroll
        for (int hh = 0; hh < 2; ++hh) {
#pragma unroll 2
            for (int d = 0; d < 34; ++d) {
                const float vp = dot36(h, wbuf + hh * 2312 + d * 68 + eo);
                const float vf = vp + __shfl_xor(vp, 1, 64);
                if (!g) myrow[d] = vf;
            }
            // both pair lanes compute the gather (identical) -> no LDS bounce
#pragma unroll
            for (int d = 0; d < 34; ++d) {
                float a = wei[hh][0] * bas[0 * ROWW + d];
                a = fmaf(wei[hh][1], bas[1 * ROWW + d], a);
                a = fmaf(wei[hh][2], bas[2 * ROWW + d], a);
                a = fmaf(wei[hh][3], bas[3 * ROWW + d], a);
                a = fmaf(wei[hh][4], bas[4 * ROWW + d], a);
                a = fmaf(wei[hh][5], bas[5 * ROWW + d], a);
                attn_own[d] = (hh == g) ? a : attn_own[d];
            }
        }

        // ---- repack to aligned e-half av[36] (R10 scheme, 2 shfls) --------
        const float a32 = __shfl_xor(attn_own[32], 1, 64);
        const float a33 = __shfl_xor(attn_own[33], 1, 64);
        float av[36];
        av[0] = g ? a32 : attn_own[0];
        av[1] = g ? a33 : attn_own[1];
#pragma unroll
        for (int j = 2; j < 32; ++j) av[j] = g ? attn_own[j - 2] : attn_own[j];
#pragma unroll
        for (int j = 32; j < 36; ++j) av[j] = g ? attn_own[j - 2] : 0.f;

        // ---- proj + residual: full p sweep so shfl pairs the SAME p -------
        STAGE1(Pw, 1156);
#pragma unroll
        for (int p = 0; p < 68; ++p) {
            const float pp = dot36(av, wbuf + p * 68 + eo);
            const float pf = pp + __shfl_xor(pp, 1, 64);
            const float yv = pf + Pb[p];
            if (p < 32) h[p]      += g ? 0.f : yv;   // g0 owns p in [0,32)
            else        h[p - 32] += g ? yv : 0.f;   // g1 owns p in [32,68)
        }
        ln68s(h, g, g1p, e1p);

        // ---- ff1 (z replicated on both lanes) + ff2 (no exchange) ---------
        STAGE2(W1, W2, 578);
        float z[34];
#pragma unroll
        for (int f = 0; f < 34; ++f) {
            const float zp = dot36(h, wbuf + f * 68 + eo);
            const float zf = zp + __shfl_xor(zp, 1, 64);
            z[f] = fmaxf(zf + b1[f], 0.f);
        }
#pragma unroll
        for (int j = 0; j < 36; ++j) {
            const int p = eo + j;
            const float yv = dot34(z, wbuf + 2312 + p * 34) + b2[p];
            h[j] += (g || j < 32) ? yv : 0.f;        // keep g0 pads at zero
        }
        ln68s(h, g, g2p, e2p);
    }

    // ---------------- final LN ----------------
    ln68s(h, g, lnf_g + eo, lnf_b + eo);

    // ---------------- fc head ----------------
    STAGE1(fc_w, 612);
    float p6[NTOK];
#pragma unroll
    for (int o = 0; o < NTOK; ++o) {
        const float pp = dot36(h, wbuf + o * 408 + t * 68 + eo);
        p6[o] = pp + __shfl_xor(pp, 1, 64);
    }
    const int base_lane = slot * 12;
    float tot[NTOK];
#pragma unroll
    for (int o = 0; o < NTOK; ++o) {
        float a = 0.f;
#pragma unroll
        for (int s = 0; s < NTOK; ++s) a += __shfl(p6[o], base_lane + 2 * s, 64);
        tot[o] = a + fc_b[o];
    }
    float myout = tot[0];
    if (t == 1) myout = tot[1];
    if (t == 2) myout = tot[2];
    if (t == 3) myout = tot[3];
    if (t == 4) myout = tot[4];
    if (t == 5) myout = tot[5];
    if (active && g == 0) out[(size_t)item * 6 + t] = fmaxf(myout, 0.f);
}

extern "C" void kernel_launch(void* const* d_in, const int* in_sizes, int n_in,
                              void* d_out, int out_size, void* d_ws, size_t ws_size,
                              hipStream_t stream) {
    const float* x      = (const float*)d_in[0];
    const float* conv_w = (const float*)d_in[1];
    const float* conv_b = (const float*)d_in[2];
    const float* lemb_w = (const float*)d_in[3];
    const float* lemb_b = (const float*)d_in[4];
    const float* wq     = (const float*)d_in[5];
    const float* wk     = (const float*)d_in[6];
    const float* wv     = (const float*)d_in[7];
    const float* proj_w = (const float*)d_in[8];
    const float* proj_b = (const float*)d_in[9];
    const float* ff1_w  = (const float*)d_in[10];
    const float* ff1_b  = (const float*)d_in[11];
    const float* ff2_w  = (const float*)d_in[12];
    const float* ff2_b  = (const float*)d_in[13];
    const float* ln1_g  = (const float*)d_in[14];
    const float* ln1_b  = (const float*)d_in[15];
    const float* ln2_g  = (const float*)d_in[16];
    const float* ln2_b  = (const float*)d_in[17];
    const float* lnf_g  = (const float*)d_in[18];
    const float* lnf_b  = (const float*)d_in[19];
    const float* fc_w   = (const float*)d_in[20];
    const float* fc_b   = (const float*)d_in[21];
    float* out = (float*)d_out;

    const int B = in_sizes[0] / (6 * 37 * 5);           // 32768
    const int blocks = (B + 19) / 20;                   // 20 items per block
    deeparcnet_fused<<<blocks, 256, 0, stream>>>(
        x, conv_w, conv_b, lemb_w, lemb_b, wq, wk, wv, proj_w, proj_b,
        ff1_w, ff1_b, ff2_w, ff2_b, ln1_g, ln1_b, ln2_g, ln2_b,
        lnf_g, lnf_b, fc_w, fc_b, out, B);
}